// Round 4
// baseline (144.364 us; speedup 1.0000x reference)
//
#include <hip/hip_runtime.h>
#include <math.h>

#define GROUPS 4
#define DCH    64
#define NBATCH 32
#define CTOT   256
#define HW     3136
#define CHW    (CTOT*HW)        /* 802816 */
#define MTOT   (NBATCH*HW)      /* 100352 */
#define EPSV   1e-5f

typedef __attribute__((ext_vector_type(8))) short bf16x8;
typedef __attribute__((ext_vector_type(4))) float f32x4;

__device__ __forceinline__ f32x4 mfma16(bf16x8 a, bf16x8 b, f32x4 c) {
    return __builtin_amdgcn_mfma_f32_16x16x32_bf16(a, b, c, 0, 0, 0);
}

// truncation split: x = hi + lo (exact), bf16(hi), bf16(lo); err <= 2^-16 |x|
__device__ __forceinline__ void split2(float x, short& h, short& l) {
    union { float f; unsigned u; } c; c.f = x;
    h = (short)(c.u >> 16);
    union { unsigned u; float f; } hm; hm.u = c.u & 0xFFFF0000u;
    union { float f; unsigned u; } lo; lo.f = x - hm.f;
    l = (short)(lo.u >> 16);
}

// ---------------------------------------------------------------------------
// K1: per-group partial Gram via bf16 hi/lo split MFMA, fragments straight
// from global. 8 waves = 4 tile-rows x 2 k-parities. Explicit 2-deep register
// double-buffer: issue k-step t+1's 8 dwordx4 before packing/MFMAing step t.
// Slab b of a wave holds rows of block (tr+b)&3 so all register indices are
// compile-time (rule #20); the permutation is undone at the LDS write.
// ---------------------------------------------------------------------------
template <int TPB>
__global__ __launch_bounds__(512) void k1_gram(const float* __restrict__ X,
                                               float* __restrict__ pGram,
                                               float* __restrict__ pSum)
{
    constexpr int TKPB = MTOT / TPB;    // cols per block
    constexpr int NK   = TKPB / 64;     // k-steps per parity wave
    const int pb   = blockIdx.x;
    const int g    = blockIdx.y;
    const int tid  = threadIdx.x;       // 0..511
    const int w    = tid >> 6;
    const int lane = tid & 63;
    const int tr   = w & 3;             // tile-row (A row-block)
    const int par  = w >> 2;            // k parity
    const int lr   = lane & 15;
    const int q    = lane >> 4;

    __shared__ float lg[2][4096];
    __shared__ float rsum[2][64];

    f32x4 acc[4];
#pragma unroll
    for (int b = 0; b < 4; ++b) acc[b] = (f32x4)(0.f);
    float sumv = 0.f;

    const float* Xg = X + (size_t)g * DCH * HW;
    float buf[2][4][8];

    // prologue: load k-step 0 into buf[0]
    {
        const int kk = pb * TKPB + par * 32;
        const int n  = kk / HW;
        const int s  = kk - n * HW;
        const float* bp = Xg + (size_t)n * CHW + s + q * 8;
#pragma unroll
        for (int b = 0; b < 4; ++b) {
            const int rb = (tr + b) & 3;
            const float* rp = bp + (size_t)(16 * rb + lr) * HW;
            float4 v0 = *reinterpret_cast<const float4*>(rp);
            float4 v1 = *reinterpret_cast<const float4*>(rp + 4);
            buf[0][b][0] = v0.x; buf[0][b][1] = v0.y; buf[0][b][2] = v0.z; buf[0][b][3] = v0.w;
            buf[0][b][4] = v1.x; buf[0][b][5] = v1.y; buf[0][b][6] = v1.z; buf[0][b][7] = v1.w;
        }
    }

#pragma unroll
    for (int t = 0; t < NK; ++t) {
        const int cb = t & 1;
        // prefetch k-step t+1
        if (t + 1 < NK) {
            const int kk = pb * TKPB + (2 * (t + 1) + par) * 32;
            const int n  = kk / HW;
            const int s  = kk - n * HW;
            const float* bp = Xg + (size_t)n * CHW + s + q * 8;
#pragma unroll
            for (int b = 0; b < 4; ++b) {
                const int rb = (tr + b) & 3;
                const float* rp = bp + (size_t)(16 * rb + lr) * HW;
                float4 v0 = *reinterpret_cast<const float4*>(rp);
                float4 v1 = *reinterpret_cast<const float4*>(rp + 4);
                buf[cb ^ 1][b][0] = v0.x; buf[cb ^ 1][b][1] = v0.y;
                buf[cb ^ 1][b][2] = v0.z; buf[cb ^ 1][b][3] = v0.w;
                buf[cb ^ 1][b][4] = v1.x; buf[cb ^ 1][b][5] = v1.y;
                buf[cb ^ 1][b][6] = v1.z; buf[cb ^ 1][b][7] = v1.w;
            }
        }
        // pack A (slab 0 = own row-block) + row-sum
        bf16x8 ah, al;
#pragma unroll
        for (int j = 0; j < 8; ++j) {
            float x = buf[cb][0][j];
            sumv += x;
            short h, l; split2(x, h, l);
            ah[j] = h; al[j] = l;
        }
        acc[0] = mfma16(ah, ah, acc[0]);
        acc[0] = mfma16(ah, al, acc[0]);
        acc[0] = mfma16(al, ah, acc[0]);
#pragma unroll
        for (int b = 1; b < 4; ++b) {
            bf16x8 bh, bl;
#pragma unroll
            for (int j = 0; j < 8; ++j) {
                short h, l; split2(buf[cb][b][j], h, l);
                bh[j] = h; bl[j] = l;
            }
            acc[b] = mfma16(ah, bh, acc[b]);
            acc[b] = mfma16(ah, bl, acc[b]);
            acc[b] = mfma16(al, bh, acc[b]);
        }
    }

    // row sums: reduce over q-quarters (lanes ^16, ^32)
    sumv += __shfl_xor(sumv, 16);
    sumv += __shfl_xor(sumv, 32);
    if (q == 0) rsum[par][16 * tr + lr] = sumv;

    // parity-split Gram partial into LDS (undo slab->colblock rotation here)
#pragma unroll
    for (int b = 0; b < 4; ++b) {
        const int cblk = (tr + b) & 3;
#pragma unroll
        for (int r = 0; r < 4; ++r) {
            int row = 16 * tr + 4 * q + r;
            int col = 16 * cblk + lr;
            lg[par][row * 64 + col] = acc[b][r];
        }
    }
    __syncthreads();

    float* pg = pGram + ((size_t)g * TPB + pb) * 4096;
    for (int i = tid; i < 4096; i += 512) pg[i] = lg[0][i] + lg[1][i];
    if (tid < 64)
        pSum[((size_t)g * TPB + pb) * 64 + tid] = rsum[0][tid] + rsum[1][tid];
}

// ---------------------------------------------------------------------------
// K2a: reduce partials -> Gram[g][4096], Mean[g][64]
// ---------------------------------------------------------------------------
__global__ __launch_bounds__(256) void k2a_reduce(const float* __restrict__ pGram,
                                                  const float* __restrict__ pSum,
                                                  float* __restrict__ Gram,
                                                  float* __restrict__ Mean,
                                                  int pbn)
{
    const int cb = blockIdx.x;   // 0..63
    const int g  = blockIdx.y;
    const int tid = threadIdx.x;
    const int e = tid & 63, q = tid >> 6;
    __shared__ float red[4][64];
    __shared__ float red2[4][64];

    const float* pg = pGram + (size_t)g * pbn * 4096 + cb * 64 + e;
    float s = 0.f;
    for (int pb = q * (pbn / 4); pb < (q + 1) * (pbn / 4); ++pb)
        s += pg[(size_t)pb * 4096];
    red[q][e] = s;
    if (cb == 0) {
        const float* ps = pSum + (size_t)g * pbn * 64 + e;
        float s2 = 0.f;
        for (int pb = q * (pbn / 4); pb < (q + 1) * (pbn / 4); ++pb)
            s2 += ps[pb * 64];
        red2[q][e] = s2;
    }
    __syncthreads();
    if (tid < 64) {
        Gram[g * 4096 + cb * 64 + tid] =
            red[0][tid] + red[1][tid] + red[2][tid] + red[3][tid];
        if (cb == 0)
            Mean[g * 64 + tid] =
                (red2[0][tid] + red2[1][tid] + red2[2][tid] + red2[3][tid]) *
                (1.0f / (float)MTOT);
    }
}

// ---------------------------------------------------------------------------
// K2b: Newton-Schulz on the matrix pipe. All iterates are symmetric (bitwise,
// by construction), so B-fragments pack from rows (contiguous k) using the
// K3-validated A/B/D layout. fp32 masters in LDS (stride 68), bf16 hi/lo
// fragments packed per matmul.
// ---------------------------------------------------------------------------
__device__ __forceinline__ void packrow2(const float* __restrict__ M, int row, int q,
                                         bf16x8& h0, bf16x8& l0,
                                         bf16x8& h1, bf16x8& l1)
{
    const float* p = M + row * 68 + 8 * q;
    float4 a0 = *reinterpret_cast<const float4*>(p);
    float4 a1 = *reinterpret_cast<const float4*>(p + 4);
    float4 b0 = *reinterpret_cast<const float4*>(p + 32);
    float4 b1 = *reinterpret_cast<const float4*>(p + 36);
    float e0[8] = {a0.x, a0.y, a0.z, a0.w, a1.x, a1.y, a1.z, a1.w};
    float e1[8] = {b0.x, b0.y, b0.z, b0.w, b1.x, b1.y, b1.z, b1.w};
#pragma unroll
    for (int j = 0; j < 8; ++j) {
        short h, l;
        split2(e0[j], h, l); h0[j] = h; l0[j] = l;
        split2(e1[j], h, l); h1[j] = h; l1[j] = l;
    }
}

// acc[c] = (A*B) tile for this wave's row-stripe; B must be symmetric.
__device__ __forceinline__ void mm_mfma(const float* __restrict__ A,
                                        const float* __restrict__ B,
                                        int w, int lr, int q, f32x4 acc[4])
{
    bf16x8 ah0, al0, ah1, al1;
    packrow2(A, 16 * w + lr, q, ah0, al0, ah1, al1);
#pragma unroll
    for (int c = 0; c < 4; ++c) {
        bf16x8 bh0, bl0, bh1, bl1;
        packrow2(B, 16 * c + lr, q, bh0, bl0, bh1, bl1);
        acc[c] = mfma16(ah0, bh0, acc[c]);
        acc[c] = mfma16(ah0, bl0, acc[c]);
        acc[c] = mfma16(al0, bh0, acc[c]);
        acc[c] = mfma16(ah1, bh1, acc[c]);
        acc[c] = mfma16(ah1, bl1, acc[c]);
        acc[c] = mfma16(al1, bh1, acc[c]);
    }
}

__global__ __launch_bounds__(256) void k2b_ns(const float* __restrict__ Gram,
                                              const float* __restrict__ Mean,
                                              const float* __restrict__ Wt,
                                              const float* __restrict__ Bs,
                                              float* __restrict__ Aout,
                                              float* __restrict__ Off)
{
    const int g   = blockIdx.x;
    const int tid = threadIdx.x;
    const int w = tid >> 6, lane = tid & 63, lr = lane & 15, q = lane >> 4;
    __shared__ float MP[64 * 68];
    __shared__ float MA[64 * 68];
    __shared__ float MB2[64 * 68];
    __shared__ float MS[64 * 68];
    __shared__ float lmean[64];
    __shared__ float redm[1024];
    __shared__ float rtr_s;

    if (tid < 64) lmean[tid] = Mean[g * 64 + tid];
    __syncthreads();
    for (int idx = tid; idx < 4096; idx += 256) {
        int d = idx >> 6, e = idx & 63;
        float v = Gram[g * 4096 + idx] * (1.0f / (float)MTOT) - lmean[d] * lmean[e];
        if (d == e) v += EPSV;
        MS[d * 68 + e] = v;
        MP[d * 68 + e] = (d == e) ? 1.f : 0.f;
    }
    __syncthreads();
    if (tid < 64) {
        float v = MS[tid * 68 + tid];
#pragma unroll
        for (int off = 32; off > 0; off >>= 1) v += __shfl_down(v, off);
        if (tid == 0) rtr_s = 1.f / v;
    }
    __syncthreads();
    const float rTr = rtr_s;
    for (int idx = tid; idx < 4096; idx += 256) {
        int d = idx >> 6, e = idx & 63;
        MS[d * 68 + e] *= rTr;
    }
    __syncthreads();

    const int row_o = 16 * w + 4 * q;
    for (int it = 0; it < 5; ++it) {
        f32x4 acc[4];
#pragma unroll
        for (int c = 0; c < 4; ++c) acc[c] = (f32x4)(0.f);
        mm_mfma(MP, MP, w, lr, q, acc);          // T1 = P*P
#pragma unroll
        for (int c = 0; c < 4; ++c)
#pragma unroll
            for (int r = 0; r < 4; ++r)
                MA[(row_o + r) * 68 + 16 * c + lr] = acc[c][r];
        __syncthreads();

#pragma unroll
        for (int c = 0; c < 4; ++c) acc[c] = (f32x4)(0.f);
        mm_mfma(MA, MP, w, lr, q, acc);          // T2 = T1*P
#pragma unroll
        for (int c = 0; c < 4; ++c)
#pragma unroll
            for (int r = 0; r < 4; ++r)
                MB2[(row_o + r) * 68 + 16 * c + lr] = acc[c][r];
        __syncthreads();

#pragma unroll
        for (int c = 0; c < 4; ++c) acc[c] = (f32x4)(0.f);
        mm_mfma(MB2, MS, w, lr, q, acc);         // P = 1.5P - 0.5*T2*Sn
#pragma unroll
        for (int c = 0; c < 4; ++c)
#pragma unroll
            for (int r = 0; r < 4; ++r) {
                int o = (row_o + r) * 68 + 16 * c + lr;
                MP[o] = 1.5f * MP[o] - 0.5f * acc[c][r];
            }
        __syncthreads();
    }

    const float sc = sqrtf(rTr);
    const int i0 = (tid >> 4) << 2, j0 = (tid & 15) << 2;
#pragma unroll
    for (int i = 0; i < 4; ++i) {
        int d = i0 + i;
        float wv = Wt[g * 64 + d] * sc;
        float4 v;
        v.x = MP[d * 68 + j0 + 0] * wv;
        v.y = MP[d * 68 + j0 + 1] * wv;
        v.z = MP[d * 68 + j0 + 2] * wv;
        v.w = MP[d * 68 + j0 + 3] * wv;
        *reinterpret_cast<float4*>(Aout + g * 4096 + (d << 6) + j0) = v;
        redm[(d << 4) + (tid & 15)] =
            v.x * lmean[j0] + v.y * lmean[j0 + 1] + v.z * lmean[j0 + 2] + v.w * lmean[j0 + 3];
    }
    __syncthreads();
    if (tid < 64) {
        float s = 0.f;
#pragma unroll
        for (int qq = 0; qq < 16; ++qq) s += redm[(tid << 4) + qq];
        Off[g * 64 + tid] = Bs[g * 64 + tid] - s;
    }
}

// ---------------------------------------------------------------------------
// K3: out = A'(x) + off via hi/lo MFMA. MFMA column-group j covers cols
// 4*lane+j -> dwordx4 loads AND stores of 4 consecutive cols per lane.
// ---------------------------------------------------------------------------
__global__ __launch_bounds__(256) void k3_apply(const float* __restrict__ X,
                                                const float* __restrict__ Aout,
                                                const float* __restrict__ Off,
                                                float* __restrict__ Y)
{
    const int bx   = blockIdx.x;        // 0..391
    const int g    = blockIdx.y;
    const int tid  = threadIdx.x;
    const int w    = tid >> 6;          // output row block 16w
    const int lane = tid & 63;
    const int lr   = lane & 15;
    const int q    = lane >> 4;

    bf16x8 ah[2], al[2];
#pragma unroll
    for (int s = 0; s < 2; ++s) {
        const float* ap = Aout + g * 4096 + (16 * w + lr) * 64 + 32 * s + 8 * q;
        float4 v0 = *reinterpret_cast<const float4*>(ap);
        float4 v1 = *reinterpret_cast<const float4*>(ap + 4);
        float av[8] = {v0.x, v0.y, v0.z, v0.w, v1.x, v1.y, v1.z, v1.w};
#pragma unroll
        for (int j = 0; j < 8; ++j) {
            short h, l; split2(av[j], h, l);
            ah[s][j] = h; al[s][j] = l;
        }
    }
    float offv[4];
#pragma unroll
    for (int r = 0; r < 4; ++r) offv[r] = Off[g * 64 + 16 * w + 4 * q + r];

    const float* Xg = X + (size_t)g * DCH * HW;
    float*       Yg = Y + (size_t)g * DCH * HW;

    for (int c = bx; c < MTOT / 64; c += 392) {
        const int col0 = c * 64;
        const int n    = col0 / HW;
        const int s0   = col0 - n * HW;
        const float* base = Xg + (size_t)n * CHW + s0 + 4 * lr;

        f32x4 accg[4];
#pragma unroll
        for (int j = 0; j < 4; ++j) accg[j] = (f32x4)(0.f);

#pragma unroll
        for (int ks = 0; ks < 2; ++ks) {
            bf16x8 bh[4], bl[4];
#pragma unroll
            for (int j8 = 0; j8 < 8; ++j8) {
                const float* xp = base + (size_t)(32 * ks + 8 * q + j8) * HW;
                float4 v = *reinterpret_cast<const float4*>(xp);
                float vv[4] = {v.x, v.y, v.z, v.w};
#pragma unroll
                for (int jj = 0; jj < 4; ++jj) {
                    short h, l; split2(vv[jj], h, l);
                    bh[jj][j8] = h; bl[jj][j8] = l;
                }
            }
#pragma unroll
            for (int jj = 0; jj < 4; ++jj) {
                accg[jj] = mfma16(ah[ks], bh[jj], accg[jj]);
                accg[jj] = mfma16(ah[ks], bl[jj], accg[jj]);
                accg[jj] = mfma16(al[ks], bh[jj], accg[jj]);
            }
        }
        float* yp = Yg + (size_t)n * CHW + s0 + 4 * lr;
#pragma unroll
        for (int r = 0; r < 4; ++r) {
            int row = 16 * w + 4 * q + r;
            float4 o;
            o.x = accg[0][r] + offv[r];
            o.y = accg[1][r] + offv[r];
            o.z = accg[2][r] + offv[r];
            o.w = accg[3][r] + offv[r];
            *reinterpret_cast<float4*>(yp + (size_t)row * HW) = o;
        }
    }
}

// ---------------------------------------------------------------------------
extern "C" void kernel_launch(void* const* d_in, const int* in_sizes, int n_in,
                              void* d_out, int out_size, void* d_ws, size_t ws_size,
                              hipStream_t stream)
{
    const float* X  = (const float*)d_in[0];
    const float* Wt = (const float*)d_in[1];
    const float* Bs = (const float*)d_in[2];
    float* Y  = (float*)d_out;
    float* ws = (float*)d_ws;

    const size_t need224 =
        ((size_t)4 * 224 * 4096 + (size_t)4 * 224 * 64 + 4 * 4096 + 256 + 4 * 4096 + 256)
        * sizeof(float);
    const int PBn = (ws_size >= need224) ? 224 : 112;

    float* pGram = ws;                                    // 4*PBn*4096
    float* pSum  = pGram + (size_t)4 * PBn * 4096;        // 4*PBn*64
    float* Gram  = pSum  + (size_t)4 * PBn * 64;          // 4*4096
    float* Mean  = Gram  + 4 * 4096;                      // 256
    float* Aout  = Mean  + 256;                           // 4*4096
    float* Off   = Aout  + 4 * 4096;                      // 256

    if (PBn == 224)
        k1_gram<224><<<dim3(224, GROUPS), 512, 0, stream>>>(X, pGram, pSum);
    else
        k1_gram<112><<<dim3(112, GROUPS), 512, 0, stream>>>(X, pGram, pSum);
    k2a_reduce<<<dim3(64, GROUPS), 256, 0, stream>>>(pGram, pSum, Gram, Mean, PBn);
    k2b_ns    <<<dim3(GROUPS), 256, 0, stream>>>(Gram, Mean, Wt, Bs, Aout, Off);
    k3_apply  <<<dim3(392, GROUPS), 256, 0, stream>>>(X, Aout, Off, Y);
}

// Round 5
// 143.988 us; speedup vs baseline: 1.0026x; 1.0026x over previous
//
#include <hip/hip_runtime.h>
#include <math.h>

#define GROUPS 4
#define DCH    64
#define NBATCH 32
#define CTOT   256
#define HW     3136
#define CHW    (CTOT*HW)        /* 802816 */
#define MTOT   (NBATCH*HW)      /* 100352 */
#define EPSV   1e-5f

typedef __attribute__((ext_vector_type(8))) short bf16x8;
typedef __attribute__((ext_vector_type(4))) float f32x4;

__device__ __forceinline__ f32x4 mfma16(bf16x8 a, bf16x8 b, f32x4 c) {
    return __builtin_amdgcn_mfma_f32_16x16x32_bf16(a, b, c, 0, 0, 0);
}

// truncation split: x = hi + lo (exact), bf16(hi), bf16(lo); err <= 2^-16 |x|
__device__ __forceinline__ void split2(float x, short& h, short& l) {
    union { float f; unsigned u; } c; c.f = x;
    h = (short)(c.u >> 16);
    union { unsigned u; float f; } hm; hm.u = c.u & 0xFFFF0000u;
    union { float f; unsigned u; } lo; lo.f = x - hm.f;
    l = (short)(lo.u >> 16);
}

// ---------------------------------------------------------------------------
// K1: per-group partial Gram via bf16 hi/lo split MFMA, fragments straight
// from global. 8 waves = 4 tile-rows x 2 k-parities. 2-deep register double
// buffer ENFORCED by sched_barrier(0): R4 showed (VGPR_Count=48) the compiler
// sinks the prefetch loads to their uses, exposing full HBM latency per slab.
// The barrier pins: loads of step t+1 are issued before compute of step t.
// ---------------------------------------------------------------------------
template <int TPB>
__global__ __launch_bounds__(512) void k1_gram(const float* __restrict__ X,
                                               float* __restrict__ pGram,
                                               float* __restrict__ pSum)
{
    constexpr int TKPB = MTOT / TPB;    // cols per block
    constexpr int NK   = TKPB / 64;     // k-steps per parity wave
    const int pb   = blockIdx.x;
    const int g    = blockIdx.y;
    const int tid  = threadIdx.x;       // 0..511
    const int w    = tid >> 6;
    const int lane = tid & 63;
    const int tr   = w & 3;             // tile-row (A row-block)
    const int par  = w >> 2;            // k parity
    const int lr   = lane & 15;
    const int q    = lane >> 4;

    __shared__ float lg[2][4096];
    __shared__ float rsum[2][64];

    f32x4 acc[4];
#pragma unroll
    for (int b = 0; b < 4; ++b) acc[b] = (f32x4)(0.f);
    float sumv = 0.f;

    const float* Xg = X + (size_t)g * DCH * HW;
    float buf[2][4][8];

    // prologue: load k-step 0 into buf[0]
    {
        const int kk = pb * TKPB + par * 32;
        const int n  = kk / HW;
        const int s  = kk - n * HW;
        const float* bp = Xg + (size_t)n * CHW + s + q * 8;
#pragma unroll
        for (int b = 0; b < 4; ++b) {
            const int rb = (tr + b) & 3;
            const float* rp = bp + (size_t)(16 * rb + lr) * HW;
            float4 v0 = *reinterpret_cast<const float4*>(rp);
            float4 v1 = *reinterpret_cast<const float4*>(rp + 4);
            buf[0][b][0] = v0.x; buf[0][b][1] = v0.y; buf[0][b][2] = v0.z; buf[0][b][3] = v0.w;
            buf[0][b][4] = v1.x; buf[0][b][5] = v1.y; buf[0][b][6] = v1.z; buf[0][b][7] = v1.w;
        }
    }

#pragma unroll
    for (int t = 0; t < NK; ++t) {
        const int cb = t & 1;           // compile-time per unrolled iter
        // prefetch k-step t+1 (issued, NOT waited here)
        if (t + 1 < NK) {
            const int kk = pb * TKPB + (2 * (t + 1) + par) * 32;
            const int n  = kk / HW;
            const int s  = kk - n * HW;
            const float* bp = Xg + (size_t)n * CHW + s + q * 8;
#pragma unroll
            for (int b = 0; b < 4; ++b) {
                const int rb = (tr + b) & 3;
                const float* rp = bp + (size_t)(16 * rb + lr) * HW;
                float4 v0 = *reinterpret_cast<const float4*>(rp);
                float4 v1 = *reinterpret_cast<const float4*>(rp + 4);
                buf[cb ^ 1][b][0] = v0.x; buf[cb ^ 1][b][1] = v0.y;
                buf[cb ^ 1][b][2] = v0.z; buf[cb ^ 1][b][3] = v0.w;
                buf[cb ^ 1][b][4] = v1.x; buf[cb ^ 1][b][5] = v1.y;
                buf[cb ^ 1][b][6] = v1.z; buf[cb ^ 1][b][7] = v1.w;
            }
        }
        __builtin_amdgcn_sched_barrier(0);   // loads stay above; compute below
        // pack A (slab 0 = own row-block) + row-sum
        bf16x8 ah, al;
#pragma unroll
        for (int j = 0; j < 8; ++j) {
            float x = buf[cb][0][j];
            sumv += x;
            short h, l; split2(x, h, l);
            ah[j] = h; al[j] = l;
        }
        acc[0] = mfma16(ah, ah, acc[0]);
        acc[0] = mfma16(ah, al, acc[0]);
        acc[0] = mfma16(al, ah, acc[0]);
#pragma unroll
        for (int b = 1; b < 4; ++b) {
            bf16x8 bh, bl;
#pragma unroll
            for (int j = 0; j < 8; ++j) {
                short h, l; split2(buf[cb][b][j], h, l);
                bh[j] = h; bl[j] = l;
            }
            acc[b] = mfma16(ah, bh, acc[b]);
            acc[b] = mfma16(ah, bl, acc[b]);
            acc[b] = mfma16(al, bh, acc[b]);
        }
        __builtin_amdgcn_sched_barrier(0);   // keep next prefetch from hoisting wait
    }

    // row sums: reduce over q-quarters (lanes ^16, ^32)
    sumv += __shfl_xor(sumv, 16);
    sumv += __shfl_xor(sumv, 32);
    if (q == 0) rsum[par][16 * tr + lr] = sumv;

    // parity-split Gram partial into LDS (undo slab->colblock rotation here)
#pragma unroll
    for (int b = 0; b < 4; ++b) {
        const int cblk = (tr + b) & 3;
#pragma unroll
        for (int r = 0; r < 4; ++r) {
            int row = 16 * tr + 4 * q + r;
            int col = 16 * cblk + lr;
            lg[par][row * 64 + col] = acc[b][r];
        }
    }
    __syncthreads();

    float* pg = pGram + ((size_t)g * TPB + pb) * 4096;
    for (int i = tid; i < 4096; i += 512) pg[i] = lg[0][i] + lg[1][i];
    if (tid < 64)
        pSum[((size_t)g * TPB + pb) * 64 + tid] = rsum[0][tid] + rsum[1][tid];
}

// ---------------------------------------------------------------------------
// K2a: reduce partials -> Gram[g][4096], Mean[g][64]
// ---------------------------------------------------------------------------
__global__ __launch_bounds__(256) void k2a_reduce(const float* __restrict__ pGram,
                                                  const float* __restrict__ pSum,
                                                  float* __restrict__ Gram,
                                                  float* __restrict__ Mean,
                                                  int pbn)
{
    const int cb = blockIdx.x;   // 0..63
    const int g  = blockIdx.y;
    const int tid = threadIdx.x;
    const int e = tid & 63, q = tid >> 6;
    __shared__ float red[4][64];
    __shared__ float red2[4][64];

    const float* pg = pGram + (size_t)g * pbn * 4096 + cb * 64 + e;
    float s = 0.f;
    for (int pb = q * (pbn / 4); pb < (q + 1) * (pbn / 4); ++pb)
        s += pg[(size_t)pb * 4096];
    red[q][e] = s;
    if (cb == 0) {
        const float* ps = pSum + (size_t)g * pbn * 64 + e;
        float s2 = 0.f;
        for (int pb = q * (pbn / 4); pb < (q + 1) * (pbn / 4); ++pb)
            s2 += ps[pb * 64];
        red2[q][e] = s2;
    }
    __syncthreads();
    if (tid < 64) {
        Gram[g * 4096 + cb * 64 + tid] =
            red[0][tid] + red[1][tid] + red[2][tid] + red[3][tid];
        if (cb == 0)
            Mean[g * 64 + tid] =
                (red2[0][tid] + red2[1][tid] + red2[2][tid] + red2[3][tid]) *
                (1.0f / (float)MTOT);
    }
}

// ---------------------------------------------------------------------------
// K2b: Newton-Schulz on the matrix pipe (symmetric iterates -> row-packed
// B-fragments legal). fp32 masters in LDS (stride 68), bf16 hi/lo per matmul.
// ---------------------------------------------------------------------------
__device__ __forceinline__ void packrow2(const float* __restrict__ M, int row, int q,
                                         bf16x8& h0, bf16x8& l0,
                                         bf16x8& h1, bf16x8& l1)
{
    const float* p = M + row * 68 + 8 * q;
    float4 a0 = *reinterpret_cast<const float4*>(p);
    float4 a1 = *reinterpret_cast<const float4*>(p + 4);
    float4 b0 = *reinterpret_cast<const float4*>(p + 32);
    float4 b1 = *reinterpret_cast<const float4*>(p + 36);
    float e0[8] = {a0.x, a0.y, a0.z, a0.w, a1.x, a1.y, a1.z, a1.w};
    float e1[8] = {b0.x, b0.y, b0.z, b0.w, b1.x, b1.y, b1.z, b1.w};
#pragma unroll
    for (int j = 0; j < 8; ++j) {
        short h, l;
        split2(e0[j], h, l); h0[j] = h; l0[j] = l;
        split2(e1[j], h, l); h1[j] = h; l1[j] = l;
    }
}

__device__ __forceinline__ void mm_mfma(const float* __restrict__ A,
                                        const float* __restrict__ B,
                                        int w, int lr, int q, f32x4 acc[4])
{
    bf16x8 ah0, al0, ah1, al1;
    packrow2(A, 16 * w + lr, q, ah0, al0, ah1, al1);
#pragma unroll
    for (int c = 0; c < 4; ++c) {
        bf16x8 bh0, bl0, bh1, bl1;
        packrow2(B, 16 * c + lr, q, bh0, bl0, bh1, bl1);
        acc[c] = mfma16(ah0, bh0, acc[c]);
        acc[c] = mfma16(ah0, bl0, acc[c]);
        acc[c] = mfma16(al0, bh0, acc[c]);
        acc[c] = mfma16(ah1, bh1, acc[c]);
        acc[c] = mfma16(ah1, bl1, acc[c]);
        acc[c] = mfma16(al1, bh1, acc[c]);
    }
}

__global__ __launch_bounds__(256) void k2b_ns(const float* __restrict__ Gram,
                                              const float* __restrict__ Mean,
                                              const float* __restrict__ Wt,
                                              const float* __restrict__ Bs,
                                              float* __restrict__ Aout,
                                              float* __restrict__ Off)
{
    const int g   = blockIdx.x;
    const int tid = threadIdx.x;
    const int w = tid >> 6, lane = tid & 63, lr = lane & 15, q = lane >> 4;
    __shared__ float MP[64 * 68];
    __shared__ float MA[64 * 68];
    __shared__ float MB2[64 * 68];
    __shared__ float MS[64 * 68];
    __shared__ float lmean[64];
    __shared__ float redm[1024];
    __shared__ float rtr_s;

    if (tid < 64) lmean[tid] = Mean[g * 64 + tid];
    __syncthreads();
    for (int idx = tid; idx < 4096; idx += 256) {
        int d = idx >> 6, e = idx & 63;
        float v = Gram[g * 4096 + idx] * (1.0f / (float)MTOT) - lmean[d] * lmean[e];
        if (d == e) v += EPSV;
        MS[d * 68 + e] = v;
        MP[d * 68 + e] = (d == e) ? 1.f : 0.f;
    }
    __syncthreads();
    if (tid < 64) {
        float v = MS[tid * 68 + tid];
#pragma unroll
        for (int off = 32; off > 0; off >>= 1) v += __shfl_down(v, off);
        if (tid == 0) rtr_s = 1.f / v;
    }
    __syncthreads();
    const float rTr = rtr_s;
    for (int idx = tid; idx < 4096; idx += 256) {
        int d = idx >> 6, e = idx & 63;
        MS[d * 68 + e] *= rTr;
    }
    __syncthreads();

    const int row_o = 16 * w + 4 * q;
    for (int it = 0; it < 5; ++it) {
        f32x4 acc[4];
#pragma unroll
        for (int c = 0; c < 4; ++c) acc[c] = (f32x4)(0.f);
        mm_mfma(MP, MP, w, lr, q, acc);          // T1 = P*P
#pragma unroll
        for (int c = 0; c < 4; ++c)
#pragma unroll
            for (int r = 0; r < 4; ++r)
                MA[(row_o + r) * 68 + 16 * c + lr] = acc[c][r];
        __syncthreads();

#pragma unroll
        for (int c = 0; c < 4; ++c) acc[c] = (f32x4)(0.f);
        mm_mfma(MA, MP, w, lr, q, acc);          // T2 = T1*P
#pragma unroll
        for (int c = 0; c < 4; ++c)
#pragma unroll
            for (int r = 0; r < 4; ++r)
                MB2[(row_o + r) * 68 + 16 * c + lr] = acc[c][r];
        __syncthreads();

#pragma unroll
        for (int c = 0; c < 4; ++c) acc[c] = (f32x4)(0.f);
        mm_mfma(MB2, MS, w, lr, q, acc);         // P = 1.5P - 0.5*T2*Sn
#pragma unroll
        for (int c = 0; c < 4; ++c)
#pragma unroll
            for (int r = 0; r < 4; ++r) {
                int o = (row_o + r) * 68 + 16 * c + lr;
                MP[o] = 1.5f * MP[o] - 0.5f * acc[c][r];
            }
        __syncthreads();
    }

    const float sc = sqrtf(rTr);
    const int i0 = (tid >> 4) << 2, j0 = (tid & 15) << 2;
#pragma unroll
    for (int i = 0; i < 4; ++i) {
        int d = i0 + i;
        float wv = Wt[g * 64 + d] * sc;
        float4 v;
        v.x = MP[d * 68 + j0 + 0] * wv;
        v.y = MP[d * 68 + j0 + 1] * wv;
        v.z = MP[d * 68 + j0 + 2] * wv;
        v.w = MP[d * 68 + j0 + 3] * wv;
        *reinterpret_cast<float4*>(Aout + g * 4096 + (d << 6) + j0) = v;
        redm[(d << 4) + (tid & 15)] =
            v.x * lmean[j0] + v.y * lmean[j0 + 1] + v.z * lmean[j0 + 2] + v.w * lmean[j0 + 3];
    }
    __syncthreads();
    if (tid < 64) {
        float s = 0.f;
#pragma unroll
        for (int qq = 0; qq < 16; ++qq) s += redm[(tid << 4) + qq];
        Off[g * 64 + tid] = Bs[g * 64 + tid] - s;
    }
}

// ---------------------------------------------------------------------------
// K3: out = A'(x) + off via hi/lo MFMA. All 16 chunk loads hoisted into
// xv[16] (static indices) + sched_barrier(0) so ONE latency exposure per
// chunk (R4 packed after each load -> per-load waitcnt serialization).
// ---------------------------------------------------------------------------
__global__ __launch_bounds__(256) void k3_apply(const float* __restrict__ X,
                                                const float* __restrict__ Aout,
                                                const float* __restrict__ Off,
                                                float* __restrict__ Y)
{
    const int bx   = blockIdx.x;        // 0..391
    const int g    = blockIdx.y;
    const int tid  = threadIdx.x;
    const int w    = tid >> 6;          // output row block 16w
    const int lane = tid & 63;
    const int lr   = lane & 15;
    const int q    = lane >> 4;

    bf16x8 ah[2], al[2];
#pragma unroll
    for (int s = 0; s < 2; ++s) {
        const float* ap = Aout + g * 4096 + (16 * w + lr) * 64 + 32 * s + 8 * q;
        float4 v0 = *reinterpret_cast<const float4*>(ap);
        float4 v1 = *reinterpret_cast<const float4*>(ap + 4);
        float av[8] = {v0.x, v0.y, v0.z, v0.w, v1.x, v1.y, v1.z, v1.w};
#pragma unroll
        for (int j = 0; j < 8; ++j) {
            short h, l; split2(av[j], h, l);
            ah[s][j] = h; al[s][j] = l;
        }
    }
    float offv[4];
#pragma unroll
    for (int r = 0; r < 4; ++r) offv[r] = Off[g * 64 + 16 * w + 4 * q + r];

    const float* Xg = X + (size_t)g * DCH * HW;
    float*       Yg = Y + (size_t)g * DCH * HW;

    for (int c = bx; c < MTOT / 64; c += 392) {
        const int col0 = c * 64;
        const int n    = col0 / HW;
        const int s0   = col0 - n * HW;
        const float* base = Xg + (size_t)n * CHW + s0 + 4 * lr;

        // issue ALL 16 loads first
        float4 xv[16];
#pragma unroll
        for (int ks = 0; ks < 2; ++ks)
#pragma unroll
            for (int j8 = 0; j8 < 8; ++j8)
                xv[ks * 8 + j8] =
                    *reinterpret_cast<const float4*>(base + (size_t)(32 * ks + 8 * q + j8) * HW);
        __builtin_amdgcn_sched_barrier(0);

        f32x4 accg[4];
#pragma unroll
        for (int j = 0; j < 4; ++j) accg[j] = (f32x4)(0.f);

#pragma unroll
        for (int ks = 0; ks < 2; ++ks) {
            bf16x8 bh[4], bl[4];
#pragma unroll
            for (int j8 = 0; j8 < 8; ++j8) {
                float4 v = xv[ks * 8 + j8];
                float vv[4] = {v.x, v.y, v.z, v.w};
#pragma unroll
                for (int jj = 0; jj < 4; ++jj) {
                    short h, l; split2(vv[jj], h, l);
                    bh[jj][j8] = h; bl[jj][j8] = l;
                }
            }
#pragma unroll
            for (int jj = 0; jj < 4; ++jj) {
                accg[jj] = mfma16(ah[ks], bh[jj], accg[jj]);
                accg[jj] = mfma16(ah[ks], bl[jj], accg[jj]);
                accg[jj] = mfma16(al[ks], bh[jj], accg[jj]);
            }
        }
        float* yp = Yg + (size_t)n * CHW + s0 + 4 * lr;
#pragma unroll
        for (int r = 0; r < 4; ++r) {
            int row = 16 * w + 4 * q + r;
            float4 o;
            o.x = accg[0][r] + offv[r];
            o.y = accg[1][r] + offv[r];
            o.z = accg[2][r] + offv[r];
            o.w = accg[3][r] + offv[r];
            *reinterpret_cast<float4*>(yp + (size_t)row * HW) = o;
        }
    }
}

// ---------------------------------------------------------------------------
extern "C" void kernel_launch(void* const* d_in, const int* in_sizes, int n_in,
                              void* d_out, int out_size, void* d_ws, size_t ws_size,
                              hipStream_t stream)
{
    const float* X  = (const float*)d_in[0];
    const float* Wt = (const float*)d_in[1];
    const float* Bs = (const float*)d_in[2];
    float* Y  = (float*)d_out;
    float* ws = (float*)d_ws;

    const size_t need224 =
        ((size_t)4 * 224 * 4096 + (size_t)4 * 224 * 64 + 4 * 4096 + 256 + 4 * 4096 + 256)
        * sizeof(float);
    const int PBn = (ws_size >= need224) ? 224 : 112;

    float* pGram = ws;                                    // 4*PBn*4096
    float* pSum  = pGram + (size_t)4 * PBn * 4096;        // 4*PBn*64
    float* Gram  = pSum  + (size_t)4 * PBn * 64;          // 4*4096
    float* Mean  = Gram  + 4 * 4096;                      // 256
    float* Aout  = Mean  + 256;                           // 4*4096
    float* Off   = Aout  + 4 * 4096;                      // 256

    if (PBn == 224)
        k1_gram<224><<<dim3(224, GROUPS), 512, 0, stream>>>(X, pGram, pSum);
    else
        k1_gram<112><<<dim3(112, GROUPS), 512, 0, stream>>>(X, pGram, pSum);
    k2a_reduce<<<dim3(64, GROUPS), 256, 0, stream>>>(pGram, pSum, Gram, Mean, PBn);
    k2b_ns    <<<dim3(GROUPS), 256, 0, stream>>>(Gram, Mean, Wt, Bs, Aout, Off);
    k3_apply  <<<dim3(392, GROUPS), 256, 0, stream>>>(X, Aout, Off, Y);
}

// Round 6
// 133.379 us; speedup vs baseline: 1.0824x; 1.0795x over previous
//
#include <hip/hip_runtime.h>
#include <math.h>

#define GROUPS 4
#define DCH    64
#define NBATCH 32
#define CTOT   256
#define HW     3136
#define CHW    (CTOT*HW)        /* 802816 */
#define MTOT   (NBATCH*HW)      /* 100352 */
#define PB1    196              /* partial k-blocks per group */
#define KPB1   (MTOT/PB1)       /* 512 cols per block */
#define NSTEP1 (KPB1/128)       /* 4 steps of 128 cols */
#define EPSV   1e-5f

typedef __attribute__((ext_vector_type(8))) short bf16x8;
typedef __attribute__((ext_vector_type(4))) float f32x4;

__device__ __forceinline__ f32x4 mfma16(bf16x8 a, bf16x8 b, f32x4 c) {
    return __builtin_amdgcn_mfma_f32_16x16x32_bf16(a, b, c, 0, 0, 0);
}

// truncation split: x = hi + lo (exact), bf16(hi), bf16(lo); err <= 2^-16 |x|
__device__ __forceinline__ void split2(float x, short& h, short& l) {
    union { float f; unsigned u; } c; c.f = x;
    h = (short)(c.u >> 16);
    union { unsigned u; float f; } hm; hm.u = c.u & 0xFFFF0000u;
    union { float f; unsigned u; } lo; lo.f = x - hm.f;
    l = (short)(lo.u >> 16);
}

// ---------------------------------------------------------------------------
// K1: per-group partial Gram. Each wave (tr,par) loads ONLY its own 16-row
// slab for its 64 parity-cols (256 B/row/step, zero redundancy), packs hi/lo
// fragments ONCE and shares them via a lane-linear LDS frag buffer. All
// waves then read the 4 slabs' fragments (conflict-free b128) + 24 MFMA.
// R5 post-mortem: the old scheme had every wave loading all 64 rows (4x
// logical demand) at 128B granules -> memory path capped at ~0.9 TB/s.
// ---------------------------------------------------------------------------
__global__ __launch_bounds__(512) void k1_gram(const float* __restrict__ X,
                                               float* __restrict__ pGram,
                                               float* __restrict__ pSum)
{
    const int pb   = blockIdx.x;        // 0..PB1-1
    const int g    = blockIdx.y;
    const int tid  = threadIdx.x;       // 0..511
    const int w    = tid >> 6;
    const int lane = tid & 63;
    const int tr   = w & 3;             // tile-row (slab this wave loads/owns)
    const int par  = w >> 2;            // which 64-col half of the 128-col step
    const int lr   = lane & 15;
    const int q    = lane >> 4;

    // frag buffer 32 KB (8192 floats), reused as lg[2][4096] in epilogue
    __shared__ float smem[8192];
    __shared__ float rsum[2][64];

    f32x4 acc[4];
#pragma unroll
    for (int c = 0; c < 4; ++c) acc[c] = (f32x4)(0.f);
    float sumv = 0.f;

    const float* Xg  = X + (size_t)g * DCH * HW;
    const int    row = 16 * tr + lr;

    float xv[16];
    // prologue: load step 0 (own slab only: row, cols par*64 + {ks*32+q*8..+7})
    {
        const int kk = pb * KPB1 + par * 64;
        const int n  = kk / HW;
        const int s  = kk - n * HW;
        const float* bp = Xg + (size_t)n * CHW + (size_t)row * HW + s + q * 8;
        float4 a0 = *reinterpret_cast<const float4*>(bp);
        float4 a1 = *reinterpret_cast<const float4*>(bp + 4);
        float4 b0 = *reinterpret_cast<const float4*>(bp + 32);
        float4 b1 = *reinterpret_cast<const float4*>(bp + 36);
        xv[0]=a0.x; xv[1]=a0.y; xv[2]=a0.z; xv[3]=a0.w;
        xv[4]=a1.x; xv[5]=a1.y; xv[6]=a1.z; xv[7]=a1.w;
        xv[8]=b0.x; xv[9]=b0.y; xv[10]=b0.z; xv[11]=b0.w;
        xv[12]=b1.x; xv[13]=b1.y; xv[14]=b1.z; xv[15]=b1.w;
    }

#pragma unroll
    for (int t = 0; t < NSTEP1; ++t) {
        // pack own fragments (consumes xv)
        bf16x8 ah[2], al[2];
#pragma unroll
        for (int ks = 0; ks < 2; ++ks) {
#pragma unroll
            for (int j = 0; j < 8; ++j) {
                float x = xv[ks * 8 + j];
                sumv += x;
                short h, l; split2(x, h, l);
                ah[ks][j] = h; al[ks][j] = l;
            }
        }
        // publish fragments: float offset (((par*4+tr)*2+ks)*2+hl)*256 + lane*4
#pragma unroll
        for (int ks = 0; ks < 2; ++ks) {
            *reinterpret_cast<bf16x8*>(&smem[(((par*4+tr)*2+ks)*2+0)*256 + lane*4]) = ah[ks];
            *reinterpret_cast<bf16x8*>(&smem[(((par*4+tr)*2+ks)*2+1)*256 + lane*4]) = al[ks];
        }
        // issue next step's loads (latency hidden under barrier+reads+MFMA)
        if (t + 1 < NSTEP1) {
            const int kk = pb * KPB1 + (t + 1) * 128 + par * 64;
            const int n  = kk / HW;
            const int s  = kk - n * HW;
            const float* bp = Xg + (size_t)n * CHW + (size_t)row * HW + s + q * 8;
            float4 a0 = *reinterpret_cast<const float4*>(bp);
            float4 a1 = *reinterpret_cast<const float4*>(bp + 4);
            float4 b0 = *reinterpret_cast<const float4*>(bp + 32);
            float4 b1 = *reinterpret_cast<const float4*>(bp + 36);
            xv[0]=a0.x; xv[1]=a0.y; xv[2]=a0.z; xv[3]=a0.w;
            xv[4]=a1.x; xv[5]=a1.y; xv[6]=a1.z; xv[7]=a1.w;
            xv[8]=b0.x; xv[9]=b0.y; xv[10]=b0.z; xv[11]=b0.w;
            xv[12]=b1.x; xv[13]=b1.y; xv[14]=b1.z; xv[15]=b1.w;
        }
        __syncthreads();
        // consume all 4 slabs' fragments
#pragma unroll
        for (int c = 0; c < 4; ++c) {
#pragma unroll
            for (int ks = 0; ks < 2; ++ks) {
                bf16x8 bh = *reinterpret_cast<const bf16x8*>(
                    &smem[(((par*4+c)*2+ks)*2+0)*256 + lane*4]);
                bf16x8 bl = *reinterpret_cast<const bf16x8*>(
                    &smem[(((par*4+c)*2+ks)*2+1)*256 + lane*4]);
                acc[c] = mfma16(ah[ks], bh, acc[c]);
                acc[c] = mfma16(ah[ks], bl, acc[c]);
                acc[c] = mfma16(al[ks], bh, acc[c]);
            }
        }
        __syncthreads();   // frag buffer reusable next step
    }

    // row sums: reduce over q-quarters
    sumv += __shfl_xor(sumv, 16);
    sumv += __shfl_xor(sumv, 32);
    if (q == 0) rsum[par][row] = sumv;

    // parity-split Gram partial into lg overlay (smem reused)
#pragma unroll
    for (int c = 0; c < 4; ++c) {
#pragma unroll
        for (int r = 0; r < 4; ++r) {
            smem[par * 4096 + (16 * tr + 4 * q + r) * 64 + 16 * c + lr] = acc[c][r];
        }
    }
    __syncthreads();

    float* pg = pGram + ((size_t)g * PB1 + pb) * 4096;
    for (int i = tid; i < 4096; i += 512) pg[i] = smem[i] + smem[4096 + i];
    if (tid < 64)
        pSum[((size_t)g * PB1 + pb) * 64 + tid] = rsum[0][tid] + rsum[1][tid];
}

// ---------------------------------------------------------------------------
// K2a: reduce partials -> Gram[g][4096], Mean[g][64]
// ---------------------------------------------------------------------------
__global__ __launch_bounds__(256) void k2a_reduce(const float* __restrict__ pGram,
                                                  const float* __restrict__ pSum,
                                                  float* __restrict__ Gram,
                                                  float* __restrict__ Mean,
                                                  int pbn)
{
    const int cb = blockIdx.x;   // 0..63
    const int g  = blockIdx.y;
    const int tid = threadIdx.x;
    const int e = tid & 63, q = tid >> 6;
    __shared__ float red[4][64];
    __shared__ float red2[4][64];

    const float* pg = pGram + (size_t)g * pbn * 4096 + cb * 64 + e;
    float s = 0.f;
    for (int pb = q * (pbn / 4); pb < (q + 1) * (pbn / 4); ++pb)
        s += pg[(size_t)pb * 4096];
    red[q][e] = s;
    if (cb == 0) {
        const float* ps = pSum + (size_t)g * pbn * 64 + e;
        float s2 = 0.f;
        for (int pb = q * (pbn / 4); pb < (q + 1) * (pbn / 4); ++pb)
            s2 += ps[pb * 64];
        red2[q][e] = s2;
    }
    __syncthreads();
    if (tid < 64) {
        Gram[g * 4096 + cb * 64 + tid] =
            red[0][tid] + red[1][tid] + red[2][tid] + red[3][tid];
        if (cb == 0)
            Mean[g * 64 + tid] =
                (red2[0][tid] + red2[1][tid] + red2[2][tid] + red2[3][tid]) *
                (1.0f / (float)MTOT);
    }
}

// ---------------------------------------------------------------------------
// K2b: Newton-Schulz on the matrix pipe (symmetric iterates -> row-packed
// B-fragments legal). fp32 masters in LDS (stride 68), bf16 hi/lo per matmul.
// ---------------------------------------------------------------------------
__device__ __forceinline__ void packrow2(const float* __restrict__ M, int row, int q,
                                         bf16x8& h0, bf16x8& l0,
                                         bf16x8& h1, bf16x8& l1)
{
    const float* p = M + row * 68 + 8 * q;
    float4 a0 = *reinterpret_cast<const float4*>(p);
    float4 a1 = *reinterpret_cast<const float4*>(p + 4);
    float4 b0 = *reinterpret_cast<const float4*>(p + 32);
    float4 b1 = *reinterpret_cast<const float4*>(p + 36);
    float e0[8] = {a0.x, a0.y, a0.z, a0.w, a1.x, a1.y, a1.z, a1.w};
    float e1[8] = {b0.x, b0.y, b0.z, b0.w, b1.x, b1.y, b1.z, b1.w};
#pragma unroll
    for (int j = 0; j < 8; ++j) {
        short h, l;
        split2(e0[j], h, l); h0[j] = h; l0[j] = l;
        split2(e1[j], h, l); h1[j] = h; l1[j] = l;
    }
}

__device__ __forceinline__ void mm_mfma(const float* __restrict__ A,
                                        const float* __restrict__ B,
                                        int w, int lr, int q, f32x4 acc[4])
{
    bf16x8 ah0, al0, ah1, al1;
    packrow2(A, 16 * w + lr, q, ah0, al0, ah1, al1);
#pragma unroll
    for (int c = 0; c < 4; ++c) {
        bf16x8 bh0, bl0, bh1, bl1;
        packrow2(B, 16 * c + lr, q, bh0, bl0, bh1, bl1);
        acc[c] = mfma16(ah0, bh0, acc[c]);
        acc[c] = mfma16(ah0, bl0, acc[c]);
        acc[c] = mfma16(al0, bh0, acc[c]);
        acc[c] = mfma16(ah1, bh1, acc[c]);
        acc[c] = mfma16(ah1, bl1, acc[c]);
        acc[c] = mfma16(al1, bh1, acc[c]);
    }
}

__global__ __launch_bounds__(256) void k2b_ns(const float* __restrict__ Gram,
                                              const float* __restrict__ Mean,
                                              const float* __restrict__ Wt,
                                              const float* __restrict__ Bs,
                                              float* __restrict__ Aout,
                                              float* __restrict__ Off)
{
    const int g   = blockIdx.x;
    const int tid = threadIdx.x;
    const int w = tid >> 6, lane = tid & 63, lr = lane & 15, q = lane >> 4;
    __shared__ float MP[64 * 68];
    __shared__ float MA[64 * 68];
    __shared__ float MB2[64 * 68];
    __shared__ float MS[64 * 68];
    __shared__ float lmean[64];
    __shared__ float redm[1024];
    __shared__ float rtr_s;

    if (tid < 64) lmean[tid] = Mean[g * 64 + tid];
    __syncthreads();
    for (int idx = tid; idx < 4096; idx += 256) {
        int d = idx >> 6, e = idx & 63;
        float v = Gram[g * 4096 + idx] * (1.0f / (float)MTOT) - lmean[d] * lmean[e];
        if (d == e) v += EPSV;
        MS[d * 68 + e] = v;
        MP[d * 68 + e] = (d == e) ? 1.f : 0.f;
    }
    __syncthreads();
    if (tid < 64) {
        float v = MS[tid * 68 + tid];
#pragma unroll
        for (int off = 32; off > 0; off >>= 1) v += __shfl_down(v, off);
        if (tid == 0) rtr_s = 1.f / v;
    }
    __syncthreads();
    const float rTr = rtr_s;
    for (int idx = tid; idx < 4096; idx += 256) {
        int d = idx >> 6, e = idx & 63;
        MS[d * 68 + e] *= rTr;
    }
    __syncthreads();

    const int row_o = 16 * w + 4 * q;
    for (int it = 0; it < 5; ++it) {
        f32x4 acc[4];
#pragma unroll
        for (int c = 0; c < 4; ++c) acc[c] = (f32x4)(0.f);
        mm_mfma(MP, MP, w, lr, q, acc);          // T1 = P*P
#pragma unroll
        for (int c = 0; c < 4; ++c)
#pragma unroll
            for (int r = 0; r < 4; ++r)
                MA[(row_o + r) * 68 + 16 * c + lr] = acc[c][r];
        __syncthreads();

#pragma unroll
        for (int c = 0; c < 4; ++c) acc[c] = (f32x4)(0.f);
        mm_mfma(MA, MP, w, lr, q, acc);          // T2 = T1*P
#pragma unroll
        for (int c = 0; c < 4; ++c)
#pragma unroll
            for (int r = 0; r < 4; ++r)
                MB2[(row_o + r) * 68 + 16 * c + lr] = acc[c][r];
        __syncthreads();

#pragma unroll
        for (int c = 0; c < 4; ++c) acc[c] = (f32x4)(0.f);
        mm_mfma(MB2, MS, w, lr, q, acc);         // P = 1.5P - 0.5*T2*Sn
#pragma unroll
        for (int c = 0; c < 4; ++c)
#pragma unroll
            for (int r = 0; r < 4; ++r) {
                int o = (row_o + r) * 68 + 16 * c + lr;
                MP[o] = 1.5f * MP[o] - 0.5f * acc[c][r];
            }
        __syncthreads();
    }

    const float sc = sqrtf(rTr);
    const int i0 = (tid >> 4) << 2, j0 = (tid & 15) << 2;
#pragma unroll
    for (int i = 0; i < 4; ++i) {
        int d = i0 + i;
        float wv = Wt[g * 64 + d] * sc;
        float4 v;
        v.x = MP[d * 68 + j0 + 0] * wv;
        v.y = MP[d * 68 + j0 + 1] * wv;
        v.z = MP[d * 68 + j0 + 2] * wv;
        v.w = MP[d * 68 + j0 + 3] * wv;
        *reinterpret_cast<float4*>(Aout + g * 4096 + (d << 6) + j0) = v;
        redm[(d << 4) + (tid & 15)] =
            v.x * lmean[j0] + v.y * lmean[j0 + 1] + v.z * lmean[j0 + 2] + v.w * lmean[j0 + 3];
    }
    __syncthreads();
    if (tid < 64) {
        float s = 0.f;
#pragma unroll
        for (int qq = 0; qq < 16; ++qq) s += redm[(tid << 4) + qq];
        Off[g * 64 + tid] = Bs[g * 64 + tid] - s;
    }
}

// ---------------------------------------------------------------------------
// K3: out = A'(x) + off. The 64x64 x-tile is staged into LDS ONCE per chunk
// (R5 had all 4 waves loading the same tile = 4x demand). Reg-staged with
// T14 split: loads for chunk t+1 issued before compute of t, ds_write after,
// double-buffered, one barrier per chunk. LDS reads are one-row-per-quarter-
// wave -> conflict-free without swizzle.
// ---------------------------------------------------------------------------
__global__ __launch_bounds__(256) void k3_apply(const float* __restrict__ X,
                                                const float* __restrict__ Aout,
                                                const float* __restrict__ Off,
                                                float* __restrict__ Y)
{
    const int bx   = blockIdx.x;        // 0..255
    const int g    = blockIdx.y;
    const int tid  = threadIdx.x;
    const int w    = tid >> 6;          // output row block 16w
    const int lane = tid & 63;
    const int lr   = lane & 15;
    const int q    = lane >> 4;

    __shared__ float tile[2][4096];     // 2 x 16 KB

    bf16x8 ah[2], al[2];
#pragma unroll
    for (int s = 0; s < 2; ++s) {
        const float* ap = Aout + g * 4096 + (16 * w + lr) * 64 + 32 * s + 8 * q;
        float4 v0 = *reinterpret_cast<const float4*>(ap);
        float4 v1 = *reinterpret_cast<const float4*>(ap + 4);
        float av[8] = {v0.x, v0.y, v0.z, v0.w, v1.x, v1.y, v1.z, v1.w};
#pragma unroll
        for (int j = 0; j < 8; ++j) {
            short h, l; split2(av[j], h, l);
            ah[s][j] = h; al[s][j] = l;
        }
    }
    float offv[4];
#pragma unroll
    for (int r = 0; r < 4; ++r) offv[r] = Off[g * 64 + 16 * w + 4 * q + r];

    const float* Xg = X + (size_t)g * DCH * HW;
    float*       Yg = Y + (size_t)g * DCH * HW;
    const int NCH = MTOT / 64;          // 1568 chunks per group

    float4 xr[4];
    // prologue: stage chunk bx
    {
        const int col0 = bx * 64;
        const int n = col0 / HW, s0 = col0 - n * HW;
        const float* base = Xg + (size_t)n * CHW + s0;
#pragma unroll
        for (int k = 0; k < 4; ++k) {
            int f = k * 256 + tid, r = f >> 4, gc = f & 15;
            xr[k] = *reinterpret_cast<const float4*>(base + (size_t)r * HW + gc * 4);
        }
    }
    {
#pragma unroll
        for (int k = 0; k < 4; ++k) {
            int f = k * 256 + tid;
            *reinterpret_cast<float4*>(&tile[0][f * 4]) = xr[k];
        }
    }
    __syncthreads();

    int cur = 0;
    for (int c = bx; c < NCH; c += 256) {
        // issue next chunk's loads (in flight under compute)
        const int cn = c + 256;
        if (cn < NCH) {
            const int col0 = cn * 64;
            const int n = col0 / HW, s0 = col0 - n * HW;
            const float* base = Xg + (size_t)n * CHW + s0;
#pragma unroll
            for (int k = 0; k < 4; ++k) {
                int f = k * 256 + tid, r = f >> 4, gc = f & 15;
                xr[k] = *reinterpret_cast<const float4*>(base + (size_t)r * HW + gc * 4);
            }
        }

        // compute from tile[cur]
        const int col0 = c * 64;
        const int n = col0 / HW, s0 = col0 - n * HW;
        f32x4 accg[4];
#pragma unroll
        for (int j = 0; j < 4; ++j) accg[j] = (f32x4)(0.f);

#pragma unroll
        for (int ks = 0; ks < 2; ++ks) {
            bf16x8 bh[4], bl[4];
#pragma unroll
            for (int j8 = 0; j8 < 8; ++j8) {
                const int row = 32 * ks + 8 * q + j8;
                float4 v = *reinterpret_cast<const float4*>(&tile[cur][row * 64 + lr * 4]);
                float vv[4] = {v.x, v.y, v.z, v.w};
#pragma unroll
                for (int jj = 0; jj < 4; ++jj) {
                    short h, l; split2(vv[jj], h, l);
                    bh[jj][j8] = h; bl[jj][j8] = l;
                }
            }
#pragma unroll
            for (int jj = 0; jj < 4; ++jj) {
                accg[jj] = mfma16(ah[ks], bh[jj], accg[jj]);
                accg[jj] = mfma16(ah[ks], bl[jj], accg[jj]);
                accg[jj] = mfma16(al[ks], bh[jj], accg[jj]);
            }
        }
        float* yp = Yg + (size_t)n * CHW + s0 + 4 * lr;
#pragma unroll
        for (int r = 0; r < 4; ++r) {
            int row = 16 * w + 4 * q + r;
            float4 o;
            o.x = accg[0][r] + offv[r];
            o.y = accg[1][r] + offv[r];
            o.z = accg[2][r] + offv[r];
            o.w = accg[3][r] + offv[r];
            *reinterpret_cast<float4*>(yp + (size_t)row * HW) = o;
        }

        // stage next chunk (waits vmcnt here, hidden under compute above)
        if (cn < NCH) {
#pragma unroll
            for (int k = 0; k < 4; ++k) {
                int f = k * 256 + tid;
                *reinterpret_cast<float4*>(&tile[cur ^ 1][f * 4]) = xr[k];
            }
        }
        __syncthreads();
        cur ^= 1;
    }
}

// ---------------------------------------------------------------------------
extern "C" void kernel_launch(void* const* d_in, const int* in_sizes, int n_in,
                              void* d_out, int out_size, void* d_ws, size_t ws_size,
                              hipStream_t stream)
{
    const float* X  = (const float*)d_in[0];
    const float* Wt = (const float*)d_in[1];
    const float* Bs = (const float*)d_in[2];
    float* Y  = (float*)d_out;
    float* ws = (float*)d_ws;

    float* pGram = ws;                                    // 4*PB1*4096
    float* pSum  = pGram + (size_t)4 * PB1 * 4096;        // 4*PB1*64
    float* Gram  = pSum  + (size_t)4 * PB1 * 64;          // 4*4096
    float* Mean  = Gram  + 4 * 4096;                      // 256
    float* Aout  = Mean  + 256;                           // 4*4096
    float* Off   = Aout  + 4 * 4096;                      // 256

    k1_gram   <<<dim3(PB1, GROUPS), 512, 0, stream>>>(X, pGram, pSum);
    k2a_reduce<<<dim3(64, GROUPS), 256, 0, stream>>>(pGram, pSum, Gram, Mean, PB1);
    k2b_ns    <<<dim3(GROUPS), 256, 0, stream>>>(Gram, Mean, Wt, Bs, Aout, Off);
    k3_apply  <<<dim3(256, GROUPS), 256, 0, stream>>>(X, Aout, Off, Y);
}